// Round 1
// baseline (1093.066 us; speedup 1.0000x reference)
//
#include <hip/hip_runtime.h>

#define GAMMA   10.0f
#define EPS_C   2.2204460492503131e-16f   // float32(7/3 - 4/3 - 1) computed in f64
#define NB      128
#define NS      128
#define ND      512
#define NN      784
#define NCOLS   (NB*NN)   // 100352

// ---------------- Kernel 1: normalize target_support rows ----------------
__global__ __launch_bounds__(128)
void tnorm_kernel(const float* __restrict__ t, float* __restrict__ tn) {
    int s = blockIdx.x;
    int tid = threadIdx.x;                       // 128 threads, 4 floats each
    float4 x = ((const float4*)(t + s * ND))[tid];
    float ss = x.x*x.x + x.y*x.y + x.z*x.z + x.w*x.w;
#pragma unroll
    for (int off = 1; off < 64; off <<= 1) ss += __shfl_xor(ss, off);
    __shared__ float red[2];
    if ((tid & 63) == 0) red[tid >> 6] = ss;
    __syncthreads();
    float tot = red[0] + red[1];
    float rs = 1.0f / sqrtf(tot);
    ((float4*)(tn + s * ND))[tid] = make_float4(x.x*rs, x.y*rs, x.z*rs, x.w*rs);
}

// ---------------- Kernel 2: C = tn . f^T, K = exp(-gamma*(2-2*C/|f|)) ----
// Tile: BM=128 (all s) x BN=128 (columns j = b*784+n), BK=16 over d.
// 256 threads, each computes 8x8. Column norms fused into the K-loop.
#define BM 128
#define BN 128
#define BK 16
#define LDP 20   // padded LDS leading dim (floats)

__global__ __launch_bounds__(256)
void gemm_k_kernel(const float* __restrict__ tn, const float* __restrict__ f,
                   float* __restrict__ Kout) {
    __shared__ float a_sh[BM * LDP];
    __shared__ float b_sh[BN * LDP];
    const int tid = threadIdx.x;
    const int j0  = blockIdx.x * BN;
    const int sx  = tid & 15;        // s sub-row
    const int nx  = tid >> 4;        // column group (0..15), 8 cols each

    float acc[8][8];
    float ssq[8];
#pragma unroll
    for (int j = 0; j < 8; j++) {
        ssq[j] = 0.0f;
#pragma unroll
        for (int i = 0; i < 8; i++) acc[i][j] = 0.0f;
    }

    for (int d0 = 0; d0 < ND; d0 += BK) {
        // stage A (t_norm) and B (features): 128 rows x 4 float4 each
#pragma unroll
        for (int l = 0; l < 2; l++) {
            int idx = tid + l * 256;
            int r   = idx >> 2;            // 0..127
            int c4  = (idx & 3) << 2;      // 0,4,8,12
            *(float4*)&a_sh[r * LDP + c4] = *(const float4*)(tn + r * ND + d0 + c4);
            *(float4*)&b_sh[r * LDP + c4] = *(const float4*)(f + (size_t)(j0 + r) * ND + d0 + c4);
        }
        __syncthreads();
#pragma unroll
        for (int k4 = 0; k4 < 4; k4++) {
            float4 av[8], bv[8];
#pragma unroll
            for (int i = 0; i < 8; i++)
                av[i] = *(const float4*)&a_sh[(sx + 16*i) * LDP + k4*4];
#pragma unroll
            for (int j = 0; j < 8; j++)
                bv[j] = *(const float4*)&b_sh[(nx*8 + j) * LDP + k4*4];
#pragma unroll
            for (int i = 0; i < 8; i++)
#pragma unroll
                for (int j = 0; j < 8; j++)
                    acc[i][j] += av[i].x*bv[j].x + av[i].y*bv[j].y
                               + av[i].z*bv[j].z + av[i].w*bv[j].w;
#pragma unroll
            for (int j = 0; j < 8; j++)
                ssq[j] += bv[j].x*bv[j].x + bv[j].y*bv[j].y
                        + bv[j].z*bv[j].z + bv[j].w*bv[j].w;
        }
        __syncthreads();
    }

    // epilogue: K[b, s, n] = exp(-gamma*(2 - 2*dot*rsqrt(ssq)))
    const int n0t = j0 + nx * 8;       // 8-aligned, 784%8==0 -> same batch/row
    const int b   = n0t / NN;
    const int n   = n0t - b * NN;
    float rsq[8];
#pragma unroll
    for (int j = 0; j < 8; j++) rsq[j] = rsqrtf(ssq[j]);
    float* outp = Kout + (size_t)b * (NS * NN) + n;
#pragma unroll
    for (int i = 0; i < 8; i++) {
        int s = sx + 16 * i;
        float vals[8];
#pragma unroll
        for (int j = 0; j < 8; j++) {
            float dot = acc[i][j] * rsq[j];
            vals[j] = __expf(-GAMMA * (2.0f - 2.0f * dot));
        }
        *(float4*)(outp + (size_t)s * NN)     = make_float4(vals[0], vals[1], vals[2], vals[3]);
        *(float4*)(outp + (size_t)s * NN + 4) = make_float4(vals[4], vals[5], vals[6], vals[7]);
    }
}

// ---------------- Kernel 3: Sinkhorn + Pi, one block per batch -----------
// LDS chunk of K_b: 128 s x TN=112 n (LDC=116 pad: float4-aligned rows,
// <=2-way bank conflicts in the v-pass with s = oct + 8*i mapping).
// One global pass over K_b per iteration: per chunk compute v (old u),
// then accumulate u-partials with the fresh v.
#define TN  112
#define LDC 116
#define NCH 7     // 784/112

__global__ __launch_bounds__(1024)
void sinkhorn_kernel(const float* __restrict__ Kg, float* __restrict__ Pi) {
    __shared__ float ch[NS * LDC];     // 59392 B
    __shared__ float u_sh[NS];
    __shared__ float uacc[NS];
    __shared__ float v_sh[NN];
    const int b    = blockIdx.x;
    const int tid  = threadIdx.x;
    const int lane = tid & 63;
    const int wid  = tid >> 6;         // 16 waves
    const float qm = 1.0f / 784.0f;
    const float pm = 1.0f / 128.0f;
    const float* Kb  = Kg + (size_t)b * (NS * NN);
    float*       Pib = Pi + (size_t)b * (NS * NN);

    if (tid < NS) u_sh[tid] = 1.0f;

    for (int it = 0; it <= 10; it++) {
        const bool last = (it == 10);
        if (tid < NS) uacc[tid] = 0.0f;
        for (int c0 = 0; c0 < NCH; c0++) {
            const int n0 = c0 * TN;
            __syncthreads();   // ch reuse + uacc reset + u_sh update visible
            // load chunk: 128 rows x 28 float4
            for (int q = tid; q < NS * 28; q += 1024) {
                int s  = q / 28;
                int c4 = (q - s * 28) << 2;
                *(float4*)&ch[s * LDC + c4] = *(const float4*)(Kb + s * NN + n0 + c4);
            }
            __syncthreads();
            // v for this chunk: c = tid>>3, 8 partial sums over s = oct+8i
            {
                int c   = tid >> 3;
                int oct = tid & 7;
                float pa = 0.0f;
                if (c < TN) {
#pragma unroll
                    for (int i = 0; i < 16; i++) {
                        int s = oct + 8 * i;
                        pa += u_sh[s] * ch[s * LDC + c];
                    }
                }
                pa += __shfl_xor(pa, 1);
                pa += __shfl_xor(pa, 2);
                pa += __shfl_xor(pa, 4);
                if (c < TN && oct == 0) v_sh[n0 + c] = qm / (pa + EPS_C);
            }
            __syncthreads();
            if (!last) {
                // u-partials: wave handles rows wid*8..wid*8+7 (no races)
#pragma unroll
                for (int rr = 0; rr < 8; rr++) {
                    int s = wid * 8 + rr;
                    float a = v_sh[n0 + lane] * ch[s * LDC + lane];
                    if (lane < 48)
                        a += v_sh[n0 + 64 + lane] * ch[s * LDC + 64 + lane];
#pragma unroll
                    for (int off = 1; off < 64; off <<= 1) a += __shfl_xor(a, off);
                    if (lane == 0) uacc[s] += a;
                }
            } else {
                // Pi = u * K * v for this chunk
                for (int q = tid; q < NS * TN; q += 1024) {
                    int s  = q / TN;
                    int cc = q - s * TN;
                    Pib[s * NN + n0 + cc] = u_sh[s] * ch[s * LDC + cc] * v_sh[n0 + cc];
                }
            }
        }
        __syncthreads();
        if (!last && tid < NS) u_sh[tid] = pm / (uacc[tid] + EPS_C);
    }
}

// ---------------- launcher ----------------
extern "C" void kernel_launch(void* const* d_in, const int* in_sizes, int n_in,
                              void* d_out, int out_size, void* d_ws, size_t ws_size,
                              hipStream_t stream) {
    const float* feat = (const float*)d_in[0];   // (128,28,28,512) f32
    const float* tsup = (const float*)d_in[1];   // (128,512) f32
    float* out = (float*)d_out;                  // (128,128,784) f32
    float* ws  = (float*)d_ws;
    float* tn   = ws;                 // 65536 floats
    float* Kbuf = ws + 65536;         // 12,845,056 floats (51.4 MB)

    tnorm_kernel<<<NS, 128, 0, stream>>>(tsup, tn);
    gemm_k_kernel<<<NCOLS / BN, 256, 0, stream>>>(tn, feat, Kbuf);
    sinkhorn_kernel<<<NB, 1024, 0, stream>>>(Kbuf, out);
}

// Round 2
// 560.087 us; speedup vs baseline: 1.9516x; 1.9516x over previous
//
#include <hip/hip_runtime.h>
#include <hip/hip_fp16.h>

#define EPS_C   2.2204460492503131e-16f
#define NS      128
#define ND      512
#define NN      784
#define NB      128
#define BSN     (NS*NN)          // 100352 elements per batch of K / Pi
#define QM      (1.0f/784.0f)
#define LOG2E20 28.853900817779268f   // 20*log2(e):  K' = exp(20*cos) = exp2(cos*this)

typedef __attribute__((ext_vector_type(8))) short bf16x8;
typedef __attribute__((ext_vector_type(4))) float f32x4;

static __device__ __forceinline__ ushort f2bf(float x) {
    uint u = __float_as_uint(x);
    uint r = (u + 0x7FFFu + ((u >> 16) & 1u)) >> 16;    // RNE
    return (ushort)r;
}
static __device__ __forceinline__ float bf2f(ushort h) {
    return __uint_as_float(((uint)h) << 16);
}

// ---------------- Kernel 1: normalize support rows, split to bf16 hi/lo ----
__global__ __launch_bounds__(128)
void tnorm_kernel(const float* __restrict__ t,
                  ushort* __restrict__ tnh, ushort* __restrict__ tnl) {
    int s = blockIdx.x, tid = threadIdx.x;
    float4 x = ((const float4*)(t + s * ND))[tid];
    float ss = x.x*x.x + x.y*x.y + x.z*x.z + x.w*x.w;
#pragma unroll
    for (int off = 1; off < 64; off <<= 1) ss += __shfl_xor(ss, off);
    __shared__ float red[2];
    if ((tid & 63) == 0) red[tid >> 6] = ss;
    __syncthreads();
    float rs = 1.0f / sqrtf(red[0] + red[1]);
    float y[4] = {x.x*rs, x.y*rs, x.z*rs, x.w*rs};
    ushort h[4], l[4];
#pragma unroll
    for (int k = 0; k < 4; k++) {
        h[k] = f2bf(y[k]);
        l[k] = f2bf(y[k] - bf2f(h[k]));
    }
    *(ushort4*)(tnh + s * ND + tid * 4) = make_ushort4(h[0], h[1], h[2], h[3]);
    *(ushort4*)(tnl + s * ND + tid * 4) = make_ushort4(l[0], l[1], l[2], l[3]);
}

// ---------------- Kernel 2: K' = exp(20*cos(t_s, f_j)) via bf16x3 MFMA -----
// Tile 128 (s) x 128 (cols j), K-chunks of 32 fp32. 256 threads = 4 waves in
// 2x2; each wave 64x64 via 4x4 grid of 16x16x32 MFMAs. 3 sweeps: HH, LH, HL.
#define LDK 40   // LDS row pitch in bf16 units (32 + 8 pad = 80 B)

__global__ __launch_bounds__(256, 3)
void gemm_k_kernel(const ushort* __restrict__ Ahi, const ushort* __restrict__ Alo,
                   const float* __restrict__ f, __half* __restrict__ Kout) {
    __shared__ ushort Ash[2][NS * LDK];   // [hi/lo][row][k]
    __shared__ ushort Bsh[2][NS * LDK];   // [hi/lo][col][k]
    __shared__ float  ssq_sh[128];

    const int tid  = threadIdx.x;
    const int lane = tid & 63;
    const int wid  = tid >> 6;
    const int wm   = wid & 1;       // row-block 0/1 (64 rows)
    const int wn   = wid >> 1;      // col-block 0/1
    const int j0   = blockIdx.x * 128;

    // staging assignments
    const int arow = tid & 127;           // A: row, half = tid>>7
    const int ahalf = tid >> 7;
    const int brow = tid >> 3;            // B: base row (0..31), 4 passes of 32
    const int bcol4 = (tid & 7) * 4;      // fp32 offset within 32-chunk

    f32x4 acc[4][4];
#pragma unroll
    for (int i = 0; i < 4; i++)
#pragma unroll
        for (int j = 0; j < 4; j++) acc[i][j] = (f32x4){0.f, 0.f, 0.f, 0.f};
    float ssqp[4] = {0.f, 0.f, 0.f, 0.f};

    const ushort* Asrc = ahalf ? Alo : Ahi;
    const int mrow = lane & 15;
    const int koff = (lane >> 4) * 8;     // 8 bf16 per lane

    for (int d0 = 0; d0 < ND; d0 += 32) {
        __syncthreads();
        // ---- stage A (pre-split bf16): 64 B per thread ----
        {
            const uint4* ap = (const uint4*)(Asrc + (size_t)arow * ND + d0);
            uint4 a0 = ap[0], a1 = ap[1], a2 = ap[2], a3 = ap[3];
            ushort* dst = &Ash[ahalf][arow * LDK];
            *(uint4*)(dst)      = a0;
            *(uint4*)(dst + 8)  = a1;
            *(uint4*)(dst + 16) = a2;
            *(uint4*)(dst + 24) = a3;
        }
        // ---- stage B (fp32 -> hi/lo bf16), fused ssq ----
#pragma unroll
        for (int p = 0; p < 4; p++) {
            int c = p * 32 + brow;
            float4 v = *(const float4*)(f + (size_t)(j0 + c) * ND + d0 + bcol4);
            ssqp[p] += v.x*v.x + v.y*v.y + v.z*v.z + v.w*v.w;
            ushort h0 = f2bf(v.x), h1 = f2bf(v.y), h2 = f2bf(v.z), h3 = f2bf(v.w);
            ushort l0 = f2bf(v.x - bf2f(h0)), l1 = f2bf(v.y - bf2f(h1));
            ushort l2 = f2bf(v.z - bf2f(h2)), l3 = f2bf(v.w - bf2f(h3));
            *(uint2*)&Bsh[0][c * LDK + bcol4] =
                make_uint2((uint)h0 | ((uint)h1 << 16), (uint)h2 | ((uint)h3 << 16));
            *(uint2*)&Bsh[1][c * LDK + bcol4] =
                make_uint2((uint)l0 | ((uint)l1 << 16), (uint)l2 | ((uint)l3 << 16));
        }
        __syncthreads();
        // ---- fragments ----
        bf16x8 ah[4], al[4], bb[4];
#pragma unroll
        for (int i = 0; i < 4; i++) {
            int r = wm * 64 + i * 16 + mrow;
            ah[i] = *(const bf16x8*)&Ash[0][r * LDK + koff];
            al[i] = *(const bf16x8*)&Ash[1][r * LDK + koff];
        }
#pragma unroll
        for (int j = 0; j < 4; j++) {
            int c = wn * 64 + j * 16 + mrow;
            bb[j] = *(const bf16x8*)&Bsh[0][c * LDK + koff];
        }
#pragma unroll
        for (int i = 0; i < 4; i++)
#pragma unroll
            for (int j = 0; j < 4; j++) {
                acc[i][j] = __builtin_amdgcn_mfma_f32_16x16x32_bf16(ah[i], bb[j], acc[i][j], 0, 0, 0);
                acc[i][j] = __builtin_amdgcn_mfma_f32_16x16x32_bf16(al[i], bb[j], acc[i][j], 0, 0, 0);
            }
#pragma unroll
        for (int j = 0; j < 4; j++) {
            int c = wn * 64 + j * 16 + mrow;
            bb[j] = *(const bf16x8*)&Bsh[1][c * LDK + koff];
        }
#pragma unroll
        for (int i = 0; i < 4; i++)
#pragma unroll
            for (int j = 0; j < 4; j++)
                acc[i][j] = __builtin_amdgcn_mfma_f32_16x16x32_bf16(ah[i], bb[j], acc[i][j], 0, 0, 0);
    }

    // ---- column-norm reduce (8 threads per column) ----
#pragma unroll
    for (int p = 0; p < 4; p++) {
#pragma unroll
        for (int off = 1; off < 8; off <<= 1) ssqp[p] += __shfl_xor(ssqp[p], off);
    }
    if ((tid & 7) == 0) {
#pragma unroll
        for (int p = 0; p < 4; p++) ssq_sh[p * 32 + (tid >> 3)] = ssqp[p];
    }
    __syncthreads();

    // ---- epilogue: K' = exp2(cos * 20*log2e), fp16 store ----
    const int quad4 = (lane >> 4) << 2;
#pragma unroll
    for (int jt = 0; jt < 4; jt++) {
        int cloc = wn * 64 + jt * 16 + mrow;
        float rq = 1.0f / sqrtf(ssq_sh[cloc]);
        int j  = j0 + cloc;
        int bb2 = j / NN;
        int nn = j - bb2 * NN;
        size_t base = (size_t)bb2 * BSN + nn;
#pragma unroll
        for (int i = 0; i < 4; i++) {
            int s0 = wm * 64 + i * 16 + quad4;
#pragma unroll
            for (int r = 0; r < 4; r++) {
                float kp = exp2f(acc[i][jt][r] * rq * LOG2E20);
                Kout[base + (size_t)(s0 + r) * NN] = __float2half(kp);
            }
        }
    }
}

// ---------------- Kernel 3: register-resident Sinkhorn (K' fp16) ----------
// 1 block / batch, 1024 threads = 16 waves. Wave w owns rows 8w..8w+7; lane l
// owns cols {l+64j}. K' regs: half2(row even, row odd) per (col, row-pair).
#define VSCALE 64.0f
#define PM64   (VSCALE/128.0f)
#define EPS64  (EPS_C*VSCALE)

__global__ __launch_bounds__(1024, 4)
void sinkhorn_kernel(const __half* __restrict__ Kh, float* __restrict__ Pi) {
    __shared__ float vsum[NN];
    __shared__ float v_sh[NN];
    const int b    = blockIdx.x;
    const int tid  = threadIdx.x;
    const int lane = tid & 63;
    const int w    = tid >> 6;
    const __half* Kb = Kh + (size_t)b * BSN;
    float* Pib = Pi + (size_t)b * BSN;

    // load K' rows 8w..8w+7, cols l+64j
    __half2 k2[13][4];
#pragma unroll
    for (int j = 0; j < 13; j++) {
        int n = lane + (j << 6);
        bool ok = (n < NN);
        int ni = ok ? n : 0;
#pragma unroll
        for (int rp = 0; rp < 4; rp++) {
            __half e = ok ? Kb[(8*w + 2*rp    ) * NN + ni] : __half(0.f);
            __half o = ok ? Kb[(8*w + 2*rp + 1) * NN + ni] : __half(0.f);
            k2[j][rp] = __halves2half2(e, o);
        }
    }

    __half2 u2[4];
    float uf[8];
#pragma unroll
    for (int rp = 0; rp < 4; rp++) u2[rp] = __halves2half2(__half(1.f), __half(1.f));
#pragma unroll
    for (int r = 0; r < 8; r++) uf[r] = 1.f;

    for (int it = 0; it <= 10; ++it) {
        if (tid < NN) vsum[tid] = 0.f;
        __syncthreads();
        // v-pass: column partial over wave's 8 rows, LDS atomic across waves
#pragma unroll
        for (int j = 0; j < 13; j++) {
            int n = lane + (j << 6);
            if (n < NN) {
                float pa = 0.f;
#pragma unroll
                for (int rp = 0; rp < 4; rp++)
                    pa = __builtin_amdgcn_fdot2(k2[j][rp], u2[rp], pa, false);
                atomicAdd(&vsum[n], pa);
            }
        }
        __syncthreads();
        if (tid < NN) v_sh[tid] = QM / (vsum[tid] + EPS_C);
        __syncthreads();
        if (it == 10) break;
        // u-pass: per-lane fp16-pair accumulate over 13 cols, wave butterfly
        __half2 acc2[4];
#pragma unroll
        for (int rp = 0; rp < 4; rp++) acc2[rp] = __halves2half2(__half(0.f), __half(0.f));
#pragma unroll
        for (int j = 0; j < 13; j++) {
            int n = lane + (j << 6);
            int ni = (n < NN) ? n : 0;
            float vv = v_sh[ni] * VSCALE;
            __half vh = __float2half(vv);
            __half2 vh2 = __halves2half2(vh, vh);
#pragma unroll
            for (int rp = 0; rp < 4; rp++)
                acc2[rp] = __hfma2(vh2, k2[j][rp], acc2[rp]);   // k2=0 for invalid n
        }
#pragma unroll
        for (int rp = 0; rp < 4; rp++) {
#pragma unroll
            for (int off = 1; off < 64; off <<= 1) {
                int xi = __shfl_xor(*(int*)&acc2[rp], off);
                acc2[rp] = __hadd2(acc2[rp], *(__half2*)&xi);
            }
            float2 af = __half22float2(acc2[rp]);
            uf[2*rp]     = PM64 / (af.x + EPS64);
            uf[2*rp + 1] = PM64 / (af.y + EPS64);
            u2[rp] = __halves2half2(__float2half(uf[2*rp]), __float2half(uf[2*rp+1]));
        }
    }

    // Pi = u * K' * v'  (scale alpha cancels exactly)
#pragma unroll
    for (int j = 0; j < 13; j++) {
        int n = lane + (j << 6);
        if (n < NN) {
            float vv = v_sh[n];
#pragma unroll
            for (int rp = 0; rp < 4; rp++) {
                float2 kk = __half22float2(k2[j][rp]);
                Pib[(size_t)(8*w + 2*rp    ) * NN + n] = uf[2*rp]     * kk.x * vv;
                Pib[(size_t)(8*w + 2*rp + 1) * NN + n] = uf[2*rp + 1] * kk.y * vv;
            }
        }
    }
}

// ---------------- launcher ----------------
extern "C" void kernel_launch(void* const* d_in, const int* in_sizes, int n_in,
                              void* d_out, int out_size, void* d_ws, size_t ws_size,
                              hipStream_t stream) {
    const float* feat = (const float*)d_in[0];   // (128,28,28,512) f32
    const float* tsup = (const float*)d_in[1];   // (128,512) f32
    float* out = (float*)d_out;                  // (128,128,784) f32

    ushort* tnh = (ushort*)d_ws;                 // 128*512 bf16
    ushort* tnl = tnh + NS * ND;
    __half* Kb  = (__half*)(tnl + NS * ND);      // 12.85M fp16 = 25.7 MB

    tnorm_kernel<<<NS, 128, 0, stream>>>(tsup, tnh, tnl);
    gemm_k_kernel<<<(NB * NN) / 128, 256, 0, stream>>>(tnh, tnl, feat, Kb);
    sinkhorn_kernel<<<NB, 1024, 0, stream>>>(Kb, out);
}

// Round 3
// 535.184 us; speedup vs baseline: 2.0424x; 1.0465x over previous
//
#include <hip/hip_runtime.h>
#include <hip/hip_fp16.h>

#define EPS_C   2.2204460492503131e-16f
#define NS      128
#define ND      512
#define NN      784
#define NB      128
#define BSN     (NS*NN)          // 100352
#define QM      (1.0f/784.0f)
#define LOG2E20 28.853900817779268f   // 20*log2(e): K' = exp(20*cos) = exp2(cos*this)

typedef __attribute__((ext_vector_type(8))) short bf16x8;
typedef __attribute__((ext_vector_type(4))) float f32x4;

static __device__ __forceinline__ ushort f2bf(float x) {
    uint u = __float_as_uint(x);
    uint r = (u + 0x7FFFu + ((u >> 16) & 1u)) >> 16;    // RNE
    return (ushort)r;
}
static __device__ __forceinline__ float bf2f(ushort h) {
    return __uint_as_float(((uint)h) << 16);
}

// ---------------- Kernel 1: normalize support rows, split to bf16 hi/lo ----
__global__ __launch_bounds__(128)
void tnorm_kernel(const float* __restrict__ t,
                  ushort* __restrict__ tnh, ushort* __restrict__ tnl) {
    int s = blockIdx.x, tid = threadIdx.x;
    float4 x = ((const float4*)(t + s * ND))[tid];
    float ss = x.x*x.x + x.y*x.y + x.z*x.z + x.w*x.w;
#pragma unroll
    for (int off = 1; off < 64; off <<= 1) ss += __shfl_xor(ss, off);
    __shared__ float red[2];
    if ((tid & 63) == 0) red[tid >> 6] = ss;
    __syncthreads();
    float rs = 1.0f / sqrtf(red[0] + red[1]);
    float y[4] = {x.x*rs, x.y*rs, x.z*rs, x.w*rs};
    ushort h[4], l[4];
#pragma unroll
    for (int k = 0; k < 4; k++) {
        h[k] = f2bf(y[k]);
        l[k] = f2bf(y[k] - bf2f(h[k]));
    }
    *(ushort4*)(tnh + s * ND + tid * 4) = make_ushort4(h[0], h[1], h[2], h[3]);
    *(ushort4*)(tnl + s * ND + tid * 4) = make_ushort4(l[0], l[1], l[2], l[3]);
}

// ---------------- Kernel 2: K' = exp(20*cos) via bf16x3 MFMA --------------
// Tile 128(s) x 128(cols), K-chunks of 32. 256 thr = 4 waves 2x2, each 64x64.
// Software-pipelined global->reg prefetch. Output written in sinkhorn-native
// packed layout: dword idx = (((b*16 + (s>>3))*13 + (n>>6))*64 + (n&63))*4
//                            + ((s&7)>>1), half2 = rows (s0, s0+1).
#define LDK 40   // LDS row pitch in bf16 units

__global__ void __launch_bounds__(256)
__attribute__((amdgpu_waves_per_eu(2, 2)))
gemm_k_kernel(const ushort* __restrict__ Ahi, const ushort* __restrict__ Alo,
              const float* __restrict__ f, uint* __restrict__ Kp) {
    __shared__ ushort Ash[2][NS * LDK];
    __shared__ ushort Bsh[2][NS * LDK];
    __shared__ float  ssq_sh[128];

    const int tid  = threadIdx.x;
    const int lane = tid & 63;
    const int wid  = tid >> 6;
    const int wm   = wid & 1;
    const int wn   = wid >> 1;
    const int j0   = blockIdx.x * 128;

    const int arow  = tid & 127;
    const int ahalf = tid >> 7;
    const int brow  = tid >> 3;
    const int bcol4 = (tid & 7) * 4;

    const ushort* Asrc = (ahalf ? Alo : Ahi) + (size_t)arow * ND;
    const float* bPtr[4];
#pragma unroll
    for (int p = 0; p < 4; p++)
        bPtr[p] = f + (size_t)(j0 + p * 32 + brow) * ND + bcol4;

    f32x4 acc[4][4];
#pragma unroll
    for (int i = 0; i < 4; i++)
#pragma unroll
        for (int j = 0; j < 4; j++) acc[i][j] = (f32x4){0.f, 0.f, 0.f, 0.f};
    float ssqp[4] = {0.f, 0.f, 0.f, 0.f};

    const int mrow = lane & 15;
    const int koff = (lane >> 4) * 8;

    // prefetch chunk 0
    uint4 aReg[4];
    float4 bReg[4];
    {
        const uint4* ap = (const uint4*)Asrc;
        aReg[0] = ap[0]; aReg[1] = ap[1]; aReg[2] = ap[2]; aReg[3] = ap[3];
#pragma unroll
        for (int p = 0; p < 4; p++) bReg[p] = *(const float4*)bPtr[p];
    }

    for (int d0 = 0; d0 < ND; d0 += 32) {
        // ---- store phase (LDS free per loop-end barrier) ----
        {
            ushort* dst = &Ash[ahalf][arow * LDK];
            *(uint4*)(dst)      = aReg[0];
            *(uint4*)(dst + 8)  = aReg[1];
            *(uint4*)(dst + 16) = aReg[2];
            *(uint4*)(dst + 24) = aReg[3];
        }
#pragma unroll
        for (int p = 0; p < 4; p++) {
            float4 v = bReg[p];
            ssqp[p] += v.x*v.x + v.y*v.y + v.z*v.z + v.w*v.w;
            ushort h0 = f2bf(v.x), h1 = f2bf(v.y), h2 = f2bf(v.z), h3 = f2bf(v.w);
            ushort l0 = f2bf(v.x - bf2f(h0)), l1 = f2bf(v.y - bf2f(h1));
            ushort l2 = f2bf(v.z - bf2f(h2)), l3 = f2bf(v.w - bf2f(h3));
            int c = p * 32 + brow;
            *(uint2*)&Bsh[0][c * LDK + bcol4] =
                make_uint2((uint)h0 | ((uint)h1 << 16), (uint)h2 | ((uint)h3 << 16));
            *(uint2*)&Bsh[1][c * LDK + bcol4] =
                make_uint2((uint)l0 | ((uint)l1 << 16), (uint)l2 | ((uint)l3 << 16));
        }
        __syncthreads();
        // ---- prefetch next chunk while MFMAs run ----
        if (d0 + 32 < ND) {
            const uint4* ap = (const uint4*)(Asrc + d0 + 32);
            aReg[0] = ap[0]; aReg[1] = ap[1]; aReg[2] = ap[2]; aReg[3] = ap[3];
#pragma unroll
            for (int p = 0; p < 4; p++)
                bReg[p] = *(const float4*)(bPtr[p] + d0 + 32);
        }
        // ---- compute: HH, LH, then HL (reuse B frags) ----
        bf16x8 ah[4], bb[4];
#pragma unroll
        for (int i = 0; i < 4; i++)
            ah[i] = *(const bf16x8*)&Ash[0][(wm*64 + i*16 + mrow) * LDK + koff];
#pragma unroll
        for (int j = 0; j < 4; j++)
            bb[j] = *(const bf16x8*)&Bsh[0][(wn*64 + j*16 + mrow) * LDK + koff];
#pragma unroll
        for (int i = 0; i < 4; i++)
#pragma unroll
            for (int j = 0; j < 4; j++)
                acc[i][j] = __builtin_amdgcn_mfma_f32_16x16x32_bf16(ah[i], bb[j], acc[i][j], 0, 0, 0);
        {
            bf16x8 al[4];
#pragma unroll
            for (int i = 0; i < 4; i++)
                al[i] = *(const bf16x8*)&Ash[1][(wm*64 + i*16 + mrow) * LDK + koff];
#pragma unroll
            for (int i = 0; i < 4; i++)
#pragma unroll
                for (int j = 0; j < 4; j++)
                    acc[i][j] = __builtin_amdgcn_mfma_f32_16x16x32_bf16(al[i], bb[j], acc[i][j], 0, 0, 0);
        }
#pragma unroll
        for (int j = 0; j < 4; j++)
            bb[j] = *(const bf16x8*)&Bsh[1][(wn*64 + j*16 + mrow) * LDK + koff];
#pragma unroll
        for (int i = 0; i < 4; i++)
#pragma unroll
            for (int j = 0; j < 4; j++)
                acc[i][j] = __builtin_amdgcn_mfma_f32_16x16x32_bf16(ah[i], bb[j], acc[i][j], 0, 0, 0);
        __syncthreads();
    }

    // ---- column-norm reduce (8 threads per column) ----
#pragma unroll
    for (int p = 0; p < 4; p++) {
#pragma unroll
        for (int off = 1; off < 8; off <<= 1) ssqp[p] += __shfl_xor(ssqp[p], off);
    }
    if ((tid & 7) == 0) {
#pragma unroll
        for (int p = 0; p < 4; p++) ssq_sh[p * 32 + (tid >> 3)] = ssqp[p];
    }
    __syncthreads();

    // ---- epilogue: K' = exp2(cos * 20log2e), packed layout, uint2 stores --
    const int quad4 = (lane >> 4) << 2;
#pragma unroll
    for (int jt = 0; jt < 4; jt++) {
        int cloc = wn * 64 + jt * 16 + mrow;
        float rq = rsqrtf(ssq_sh[cloc]) * LOG2E20;
        int jg = j0 + cloc;
        int b2 = jg / NN;
        int nn = jg - b2 * NN;
        int jj = nn >> 6, l = nn & 63;
#pragma unroll
        for (int i = 0; i < 4; i++) {
            int s0 = wm * 64 + i * 16 + quad4;      // s0 % 4 == 0
            float k0 = exp2f(acc[i][jt][0] * rq);
            float k1 = exp2f(acc[i][jt][1] * rq);
            float k2v = exp2f(acc[i][jt][2] * rq);
            float k3 = exp2f(acc[i][jt][3] * rq);
            __half2 lo = __halves2half2(__float2half(k0), __float2half(k1));
            __half2 hi = __halves2half2(__float2half(k2v), __float2half(k3));
            size_t dw = (((size_t)(b2 * 16 + (s0 >> 3)) * 13 + jj) * 64 + l) * 4
                        + ((s0 & 7) >> 1);
            *(uint2*)(Kp + dw) = make_uint2(__builtin_bit_cast(uint, lo),
                                            __builtin_bit_cast(uint, hi));
        }
    }
}

// ---------------- Kernel 3: register-resident Sinkhorn (packed K' fp16) ---
// 1 block/batch, 1024 thr = 16 waves. Wave w owns rows 8w..8w+7; lane l owns
// cols {l+64j}. k2[j][rp] = half2(row 8w+2rp, row 8w+2rp+1) at col l+64j.
#define VSCALE 64.0f
#define PM64   (VSCALE/128.0f)
#define EPS64  (EPS_C*VSCALE)

__global__ void __launch_bounds__(1024)
__attribute__((amdgpu_waves_per_eu(4, 4)))
sinkhorn_kernel(const uint* __restrict__ Kp, float* __restrict__ Pi) {
    __shared__ float vsum[NN];
    __shared__ float v_sh[NN];
    const int b    = blockIdx.x;
    const int tid  = threadIdx.x;
    const int lane = tid & 63;
    const int w    = tid >> 6;
    float* Pib = Pi + (size_t)b * BSN;

    // coalesced dwordx4 loads: 13 per thread
    const uint4* kbase = (const uint4*)Kp + (size_t)(b * 16 + w) * 13 * 64 + lane;
    __half2 k2[13][4];
#pragma unroll
    for (int j = 0; j < 13; j++) {
        uint4 t = kbase[j * 64];
        k2[j][0] = __builtin_bit_cast(__half2, t.x);
        k2[j][1] = __builtin_bit_cast(__half2, t.y);
        k2[j][2] = __builtin_bit_cast(__half2, t.z);
        k2[j][3] = __builtin_bit_cast(__half2, t.w);
    }
    if (lane >= 16) {   // padded tail: n = lane+768 >= 784
#pragma unroll
        for (int rp = 0; rp < 4; rp++) k2[12][rp] = __halves2half2(__half(0.f), __half(0.f));
    }

    __half2 u2[4];
    float uf[8];
#pragma unroll
    for (int rp = 0; rp < 4; rp++) u2[rp] = __halves2half2(__half(1.f), __half(1.f));
#pragma unroll
    for (int r = 0; r < 8; r++) uf[r] = 1.f;

    for (int it = 0; it <= 10; ++it) {
        if (tid < NN) vsum[tid] = 0.f;
        __syncthreads();
        // v-pass: per-column partial over this wave's 8 rows, LDS atomic
#pragma unroll
        for (int j = 0; j < 13; j++) {
            int n = lane + (j << 6);
            float pa = 0.f;
#pragma unroll
            for (int rp = 0; rp < 4; rp++)
                pa = __builtin_amdgcn_fdot2(k2[j][rp], u2[rp], pa, false);
            if (n < NN) atomicAdd(&vsum[n], pa);
        }
        __syncthreads();
        if (tid < NN) v_sh[tid] = QM / (vsum[tid] + EPS_C);
        __syncthreads();
        if (it == 10) break;
        // u-pass: fp16-pair accumulate over 13 cols, 64-lane butterfly
        __half2 acc2[4];
#pragma unroll
        for (int rp = 0; rp < 4; rp++) acc2[rp] = __halves2half2(__half(0.f), __half(0.f));
#pragma unroll
        for (int j = 0; j < 13; j++) {
            int n = lane + (j << 6);
            int ni = (n < NN) ? n : 0;
            float vv = v_sh[ni] * VSCALE;
            __half vh = __float2half(vv);
            __half2 vh2 = __halves2half2(vh, vh);
#pragma unroll
            for (int rp = 0; rp < 4; rp++)
                acc2[rp] = __hfma2(vh2, k2[j][rp], acc2[rp]);   // k2==0 masks tail
        }
#pragma unroll
        for (int rp = 0; rp < 4; rp++) {
#pragma unroll
            for (int off = 1; off < 64; off <<= 1) {
                int y = __shfl_xor(__builtin_bit_cast(int, acc2[rp]), off);
                acc2[rp] = __hadd2(acc2[rp], __builtin_bit_cast(__half2, y));
            }
            float2 af = __half22float2(acc2[rp]);
            uf[2*rp]     = PM64 / (af.x + EPS64);
            uf[2*rp + 1] = PM64 / (af.y + EPS64);
            u2[rp] = __halves2half2(__float2half(uf[2*rp]), __float2half(uf[2*rp+1]));
        }
    }

    // Pi = u * K' * v'  (K'-scale cancels exactly)
#pragma unroll
    for (int j = 0; j < 13; j++) {
        int n = lane + (j << 6);
        if (n < NN) {
            float vv = v_sh[n];
#pragma unroll
            for (int rp = 0; rp < 4; rp++) {
                float2 kk = __half22float2(k2[j][rp]);
                Pib[(size_t)(8*w + 2*rp    ) * NN + n] = uf[2*rp]     * kk.x * vv;
                Pib[(size_t)(8*w + 2*rp + 1) * NN + n] = uf[2*rp + 1] * kk.y * vv;
            }
        }
    }
}

// ---------------- launcher ----------------
extern "C" void kernel_launch(void* const* d_in, const int* in_sizes, int n_in,
                              void* d_out, int out_size, void* d_ws, size_t ws_size,
                              hipStream_t stream) {
    const float* feat = (const float*)d_in[0];   // (128,28,28,512) f32
    const float* tsup = (const float*)d_in[1];   // (128,512) f32
    float* out = (float*)d_out;                  // (128,128,784) f32

    ushort* tnh = (ushort*)d_ws;                 // 128*512 bf16
    ushort* tnl = tnh + NS * ND;
    uint*   Kp  = (uint*)(tnl + NS * ND);        // 128*16*13*64*4 dwords = 27.3 MB

    tnorm_kernel<<<NS, 128, 0, stream>>>(tsup, tnh, tnl);
    gemm_k_kernel<<<(NB * NN) / 128, 256, 0, stream>>>(tnh, tnl, feat, Kp);
    sinkhorn_kernel<<<NB, 1024, 0, stream>>>(Kp, out);
}

// Round 4
// 378.236 us; speedup vs baseline: 2.8899x; 1.4149x over previous
//
#include <hip/hip_runtime.h>
#include <hip/hip_fp16.h>

#define EPS_C   2.2204460492503131e-16f
#define NS      128
#define ND      512
#define NN      784
#define NB      128
#define BSN     (NS*NN)          // 100352
#define QM      (1.0f/784.0f)
#define LOG2E20 28.853900817779268f   // 20*log2(e): K' = exp(20*cos) = exp2(cos*this)

typedef __attribute__((ext_vector_type(8))) short bf16x8;
typedef __attribute__((ext_vector_type(4))) float f32x4;

static __device__ __forceinline__ ushort f2bf(float x) {
    uint u = __float_as_uint(x);
    uint r = (u + 0x7FFFu + ((u >> 16) & 1u)) >> 16;    // RNE
    return (ushort)r;
}
static __device__ __forceinline__ float bf2f(ushort h) {
    return __uint_as_float(((uint)h) << 16);
}

// ---------------- Kernel 1: normalize support rows, split to bf16 hi/lo ----
__global__ __launch_bounds__(128)
void tnorm_kernel(const float* __restrict__ t,
                  ushort* __restrict__ tnh, ushort* __restrict__ tnl) {
    int s = blockIdx.x, tid = threadIdx.x;
    float4 x = ((const float4*)(t + s * ND))[tid];
    float ss = x.x*x.x + x.y*x.y + x.z*x.z + x.w*x.w;
#pragma unroll
    for (int off = 1; off < 64; off <<= 1) ss += __shfl_xor(ss, off);
    __shared__ float red[2];
    if ((tid & 63) == 0) red[tid >> 6] = ss;
    __syncthreads();
    float rs = 1.0f / sqrtf(red[0] + red[1]);
    float y[4] = {x.x*rs, x.y*rs, x.z*rs, x.w*rs};
    ushort h[4], l[4];
#pragma unroll
    for (int k = 0; k < 4; k++) {
        h[k] = f2bf(y[k]);
        l[k] = f2bf(y[k] - bf2f(h[k]));
    }
    *(ushort4*)(tnh + s * ND + tid * 4) = make_ushort4(h[0], h[1], h[2], h[3]);
    *(ushort4*)(tnl + s * ND + tid * 4) = make_ushort4(l[0], l[1], l[2], l[3]);
}

// ---------------- Kernel 2: K' = exp(20*cos) via bf16x3 MFMA --------------
// (unchanged from round 3 for clean attribution of the sinkhorn change)
#define LDK 40   // LDS row pitch in bf16 units

__global__ void __launch_bounds__(256)
__attribute__((amdgpu_waves_per_eu(2, 2)))
gemm_k_kernel(const ushort* __restrict__ Ahi, const ushort* __restrict__ Alo,
              const float* __restrict__ f, uint* __restrict__ Kp) {
    __shared__ ushort Ash[2][NS * LDK];
    __shared__ ushort Bsh[2][NS * LDK];
    __shared__ float  ssq_sh[128];

    const int tid  = threadIdx.x;
    const int lane = tid & 63;
    const int wid  = tid >> 6;
    const int wm   = wid & 1;
    const int wn   = wid >> 1;
    const int j0   = blockIdx.x * 128;

    const int arow  = tid & 127;
    const int ahalf = tid >> 7;
    const int brow  = tid >> 3;
    const int bcol4 = (tid & 7) * 4;

    const ushort* Asrc = (ahalf ? Alo : Ahi) + (size_t)arow * ND;
    const float* bPtr[4];
#pragma unroll
    for (int p = 0; p < 4; p++)
        bPtr[p] = f + (size_t)(j0 + p * 32 + brow) * ND + bcol4;

    f32x4 acc[4][4];
#pragma unroll
    for (int i = 0; i < 4; i++)
#pragma unroll
        for (int j = 0; j < 4; j++) acc[i][j] = (f32x4){0.f, 0.f, 0.f, 0.f};
    float ssqp[4] = {0.f, 0.f, 0.f, 0.f};

    const int mrow = lane & 15;
    const int koff = (lane >> 4) * 8;

    // prefetch chunk 0
    uint4 aReg[4];
    float4 bReg[4];
    {
        const uint4* ap = (const uint4*)Asrc;
        aReg[0] = ap[0]; aReg[1] = ap[1]; aReg[2] = ap[2]; aReg[3] = ap[3];
#pragma unroll
        for (int p = 0; p < 4; p++) bReg[p] = *(const float4*)bPtr[p];
    }

    for (int d0 = 0; d0 < ND; d0 += 32) {
        // ---- store phase ----
        {
            ushort* dst = &Ash[ahalf][arow * LDK];
            *(uint4*)(dst)      = aReg[0];
            *(uint4*)(dst + 8)  = aReg[1];
            *(uint4*)(dst + 16) = aReg[2];
            *(uint4*)(dst + 24) = aReg[3];
        }
#pragma unroll
        for (int p = 0; p < 4; p++) {
            float4 v = bReg[p];
            ssqp[p] += v.x*v.x + v.y*v.y + v.z*v.z + v.w*v.w;
            ushort h0 = f2bf(v.x), h1 = f2bf(v.y), h2 = f2bf(v.z), h3 = f2bf(v.w);
            ushort l0 = f2bf(v.x - bf2f(h0)), l1 = f2bf(v.y - bf2f(h1));
            ushort l2 = f2bf(v.z - bf2f(h2)), l3 = f2bf(v.w - bf2f(h3));
            int c = p * 32 + brow;
            *(uint2*)&Bsh[0][c * LDK + bcol4] =
                make_uint2((uint)h0 | ((uint)h1 << 16), (uint)h2 | ((uint)h3 << 16));
            *(uint2*)&Bsh[1][c * LDK + bcol4] =
                make_uint2((uint)l0 | ((uint)l1 << 16), (uint)l2 | ((uint)l3 << 16));
        }
        __syncthreads();
        // ---- prefetch next chunk while MFMAs run ----
        if (d0 + 32 < ND) {
            const uint4* ap = (const uint4*)(Asrc + d0 + 32);
            aReg[0] = ap[0]; aReg[1] = ap[1]; aReg[2] = ap[2]; aReg[3] = ap[3];
#pragma unroll
            for (int p = 0; p < 4; p++)
                bReg[p] = *(const float4*)(bPtr[p] + d0 + 32);
        }
        // ---- compute: HH, LH, then HL ----
        bf16x8 ah[4], bb[4];
#pragma unroll
        for (int i = 0; i < 4; i++)
            ah[i] = *(const bf16x8*)&Ash[0][(wm*64 + i*16 + mrow) * LDK + koff];
#pragma unroll
        for (int j = 0; j < 4; j++)
            bb[j] = *(const bf16x8*)&Bsh[0][(wn*64 + j*16 + mrow) * LDK + koff];
#pragma unroll
        for (int i = 0; i < 4; i++)
#pragma unroll
            for (int j = 0; j < 4; j++)
                acc[i][j] = __builtin_amdgcn_mfma_f32_16x16x32_bf16(ah[i], bb[j], acc[i][j], 0, 0, 0);
        {
            bf16x8 al[4];
#pragma unroll
            for (int i = 0; i < 4; i++)
                al[i] = *(const bf16x8*)&Ash[1][(wm*64 + i*16 + mrow) * LDK + koff];
#pragma unroll
            for (int i = 0; i < 4; i++)
#pragma unroll
                for (int j = 0; j < 4; j++)
                    acc[i][j] = __builtin_amdgcn_mfma_f32_16x16x32_bf16(al[i], bb[j], acc[i][j], 0, 0, 0);
        }
#pragma unroll
        for (int j = 0; j < 4; j++)
            bb[j] = *(const bf16x8*)&Bsh[1][(wn*64 + j*16 + mrow) * LDK + koff];
#pragma unroll
        for (int i = 0; i < 4; i++)
#pragma unroll
            for (int j = 0; j < 4; j++)
                acc[i][j] = __builtin_amdgcn_mfma_f32_16x16x32_bf16(ah[i], bb[j], acc[i][j], 0, 0, 0);
        __syncthreads();
    }

    // ---- column-norm reduce ----
#pragma unroll
    for (int p = 0; p < 4; p++) {
#pragma unroll
        for (int off = 1; off < 8; off <<= 1) ssqp[p] += __shfl_xor(ssqp[p], off);
    }
    if ((tid & 7) == 0) {
#pragma unroll
        for (int p = 0; p < 4; p++) ssq_sh[p * 32 + (tid >> 3)] = ssqp[p];
    }
    __syncthreads();

    // ---- epilogue: K' packed for sinkhorn ----
    const int quad4 = (lane >> 4) << 2;
#pragma unroll
    for (int jt = 0; jt < 4; jt++) {
        int cloc = wn * 64 + jt * 16 + mrow;
        float rq = rsqrtf(ssq_sh[cloc]) * LOG2E20;
        int jg = j0 + cloc;
        int b2 = jg / NN;
        int nn = jg - b2 * NN;
        int jj = nn >> 6, l = nn & 63;
#pragma unroll
        for (int i = 0; i < 4; i++) {
            int s0 = wm * 64 + i * 16 + quad4;      // s0 % 4 == 0
            float k0 = exp2f(acc[i][jt][0] * rq);
            float k1 = exp2f(acc[i][jt][1] * rq);
            float k2v = exp2f(acc[i][jt][2] * rq);
            float k3 = exp2f(acc[i][jt][3] * rq);
            __half2 lo = __halves2half2(__float2half(k0), __float2half(k1));
            __half2 hi = __halves2half2(__float2half(k2v), __float2half(k3));
            size_t dw = (((size_t)(b2 * 16 + (s0 >> 3)) * 13 + jj) * 64 + l) * 4
                        + ((s0 & 7) >> 1);
            *(uint2*)(Kp + dw) = make_uint2(__builtin_bit_cast(uint, lo),
                                            __builtin_bit_cast(uint, hi));
        }
    }
}

// ---------------- Kernel 3: register-resident Sinkhorn, atomic-free -------
// 1 block/batch, 1024 thr = 16 waves. Wave w owns rows 8w..8w+7; lane l owns
// cols {l+64j}. v-reduction: per-wave partials -> LDS slab[16][784], then 784
// threads sum 16 rows each (conflict-free; no atomics, no CAS retries).
// 2 barriers/iteration: B1 publishes slab, B2 publishes v_sh AND guarantees
// slab reads done before next iteration overwrites it.
#define VSCALE 64.0f
#define PM64   (VSCALE/128.0f)
#define EPS64  (EPS_C*VSCALE)

__global__ void __launch_bounds__(1024)
__attribute__((amdgpu_waves_per_eu(4, 4)))
sinkhorn_kernel(const uint* __restrict__ Kp, float* __restrict__ Pi) {
    __shared__ float slab[16 * NN];   // 50176 B
    __shared__ float v_sh[NN];
    const int b    = blockIdx.x;
    const int tid  = threadIdx.x;
    const int lane = tid & 63;
    const int w    = tid >> 6;
    float* Pib = Pi + (size_t)b * BSN;

    // coalesced dwordx4 loads: 13 per thread
    const uint4* kbase = (const uint4*)Kp + (size_t)(b * 16 + w) * 13 * 64 + lane;
    __half2 k2[13][4];
#pragma unroll
    for (int j = 0; j < 13; j++) {
        uint4 t = kbase[j * 64];
        k2[j][0] = __builtin_bit_cast(__half2, t.x);
        k2[j][1] = __builtin_bit_cast(__half2, t.y);
        k2[j][2] = __builtin_bit_cast(__half2, t.z);
        k2[j][3] = __builtin_bit_cast(__half2, t.w);
    }
    if (lane >= 16) {   // padded tail: n = lane+768 >= 784
#pragma unroll
        for (int rp = 0; rp < 4; rp++) k2[12][rp] = __halves2half2(__half(0.f), __half(0.f));
    }

    __half2 u2[4];
    float uf[8];
#pragma unroll
    for (int rp = 0; rp < 4; rp++) u2[rp] = __halves2half2(__half(1.f), __half(1.f));
#pragma unroll
    for (int r = 0; r < 8; r++) uf[r] = 1.f;

    float* myrow = &slab[w * NN];

    for (int it = 0; it <= 10; ++it) {
        // v-pass: per-wave column partials -> private slab row (no atomics)
#pragma unroll
        for (int j = 0; j < 13; j++) {
            int n = lane + (j << 6);
            float pa = 0.f;
#pragma unroll
            for (int rp = 0; rp < 4; rp++)
                pa = __builtin_amdgcn_fdot2(k2[j][rp], u2[rp], pa, false);
            if (n < NN) myrow[n] = pa;
        }
        __syncthreads();                         // B1: slab published
        // phase 2: 784 threads each sum 16 slab rows
        if (tid < NN) {
            float s0 = 0.f, s1 = 0.f, s2 = 0.f, s3 = 0.f;
#pragma unroll
            for (int w2 = 0; w2 < 16; w2 += 4) {
                s0 += slab[(w2 + 0) * NN + tid];
                s1 += slab[(w2 + 1) * NN + tid];
                s2 += slab[(w2 + 2) * NN + tid];
                s3 += slab[(w2 + 3) * NN + tid];
            }
            v_sh[tid] = QM / (((s0 + s1) + (s2 + s3)) + EPS_C);
        }
        __syncthreads();                         // B2: v_sh ready, slab reads done
        if (it == 10) break;
        // u-pass: fp16-pair accumulate over 13 cols, 64-lane butterfly
        __half2 acc2[4];
#pragma unroll
        for (int rp = 0; rp < 4; rp++) acc2[rp] = __halves2half2(__half(0.f), __half(0.f));
#pragma unroll
        for (int j = 0; j < 13; j++) {
            int n = lane + (j << 6);
            int ni = (n < NN) ? n : 0;
            float vv = v_sh[ni] * VSCALE;
            __half vh = __float2half(vv);
            __half2 vh2 = __halves2half2(vh, vh);
#pragma unroll
            for (int rp = 0; rp < 4; rp++)
                acc2[rp] = __hfma2(vh2, k2[j][rp], acc2[rp]);   // k2==0 masks tail
        }
#pragma unroll
        for (int rp = 0; rp < 4; rp++) {
#pragma unroll
            for (int off = 1; off < 64; off <<= 1) {
                int y = __shfl_xor(__builtin_bit_cast(int, acc2[rp]), off);
                acc2[rp] = __hadd2(acc2[rp], __builtin_bit_cast(__half2, y));
            }
            float2 af = __half22float2(acc2[rp]);
            uf[2*rp]     = PM64 / (af.x + EPS64);
            uf[2*rp + 1] = PM64 / (af.y + EPS64);
            u2[rp] = __halves2half2(__float2half(uf[2*rp]), __float2half(uf[2*rp+1]));
        }
    }

    // Pi = u * K' * v'  (K'-scale cancels exactly)
#pragma unroll
    for (int j = 0; j < 13; j++) {
        int n = lane + (j << 6);
        if (n < NN) {
            float vv = v_sh[n];
#pragma unroll
            for (int rp = 0; rp < 4; rp++) {
                float2 kk = __half22float2(k2[j][rp]);
                Pib[(size_t)(8*w + 2*rp    ) * NN + n] = uf[2*rp]     * kk.x * vv;
                Pib[(size_t)(8*w + 2*rp + 1) * NN + n] = uf[2*rp + 1] * kk.y * vv;
            }
        }
    }
}

// ---------------- launcher ----------------
extern "C" void kernel_launch(void* const* d_in, const int* in_sizes, int n_in,
                              void* d_out, int out_size, void* d_ws, size_t ws_size,
                              hipStream_t stream) {
    const float* feat = (const float*)d_in[0];   // (128,28,28,512) f32
    const float* tsup = (const float*)d_in[1];   // (128,512) f32
    float* out = (float*)d_out;                  // (128,128,784) f32

    ushort* tnh = (ushort*)d_ws;                 // 128*512 bf16
    ushort* tnl = tnh + NS * ND;
    uint*   Kp  = (uint*)(tnl + NS * ND);        // 128*16*13*64*4 dwords = 27.3 MB

    tnorm_kernel<<<NS, 128, 0, stream>>>(tsup, tnh, tnl);
    gemm_k_kernel<<<(NB * NN) / 128, 256, 0, stream>>>(tnh, tnl, feat, Kp);
    sinkhorn_kernel<<<NB, 1024, 0, stream>>>(Kp, out);
}